// Round 1
// baseline (602.925 us; speedup 1.0000x reference)
//
#include <hip/hip_runtime.h>
#include <math.h>

// Problem constants (fixed by the reference):
//   tokens M = 4*128*128 = 65536, dim = 256, H = 8 heads, hd = 32
//   q,k,vv = v @ Wq/Wk/Wv ; per-token 8x8 attention over HEADS axis;
//   out = (attn @ vv) @ Wp + bp.  Everything is per-token -> full fusion.

#define DIMX      256
#define NHEADS    8
#define HDIM      32
#define TM        16      // tokens per workgroup
#define NTHREADS  256
#define VSTRIDE   260     // v-tile row stride (floats), 260%32=4 -> staggered banks
#define ROWSTRIDE 784     // qkv row stride (floats): q@+0, k@+260, vv@+520, 784%4==0

__global__ __launch_bounds__(NTHREADS, 3)
void fused_selfattn(const float* __restrict__ v,
                    const float* __restrict__ Wq,
                    const float* __restrict__ Wk,
                    const float* __restrict__ Wv,
                    const float* __restrict__ Wp,
                    const float* __restrict__ bp,
                    float* __restrict__ out)
{
    // LDS: stage 0/1 uses v_s(t,k) = smem[t*260 + k]  (16x256)
    //      stage 2+ uses qkv rows: smem[t*784 + {0,260,520} + c]
    //      x_s(t,c) aliases the q section (written after all q reads done)
    __shared__ __align__(16) float smem[TM * ROWSTRIDE];

    const int tid = threadIdx.x;
    const long token0 = (long)blockIdx.x * TM;

    // ---------------- stage 0: load v tile, coalesced float4 ----------------
    {
        const float4* vsrc = (const float4*)(v + token0 * DIMX);
#pragma unroll
        for (int i = 0; i < 4; ++i) {
            int u = tid + NTHREADS * i;   // 0..1023 float4 slots (16 tok x 64)
            int t = u >> 6;
            int f = u & 63;
            float4 val = vsrc[u];
            *(float4*)&smem[t * VSTRIDE + 4 * f] = val;
        }
    }
    __syncthreads();

    // ---------------- stage 1: qkv = v @ [Wq|Wk|Wv] --------------------------
    // Thread tile: 4 tokens x 4 cols x 3 matrices, acc in regs (48 floats).
    const int t_blk = tid & 3;        // 0..3
    const int j_idx = tid >> 2;       // 0..63
    const int t0 = 4 * t_blk;
    const int c0 = 4 * j_idx;         // column within each 256-wide matrix

    float acc[3][4][4];
#pragma unroll
    for (int p = 0; p < 3; ++p)
#pragma unroll
        for (int t = 0; t < 4; ++t)
#pragma unroll
            for (int j = 0; j < 4; ++j)
                acc[p][t][j] = 0.f;

    const float* Wbase0 = Wq + c0;
    const float* Wbase1 = Wk + c0;
    const float* Wbase2 = Wv + c0;

    for (int k = 0; k < DIMX; k += 4) {
        float va[4][4];
#pragma unroll
        for (int t = 0; t < 4; ++t) {
            float4 tmp = *(const float4*)&smem[(t0 + t) * VSTRIDE + k];
            va[t][0] = tmp.x; va[t][1] = tmp.y; va[t][2] = tmp.z; va[t][3] = tmp.w;
        }
        const float* wrow[3];
        wrow[0] = Wbase0 + (size_t)k * DIMX;
        wrow[1] = Wbase1 + (size_t)k * DIMX;
        wrow[2] = Wbase2 + (size_t)k * DIMX;
#pragma unroll
        for (int p = 0; p < 3; ++p) {
            float wv[4][4];  // wv[kk][jj]
#pragma unroll
            for (int kk = 0; kk < 4; ++kk) {
                float4 tmp = *(const float4*)(wrow[p] + (size_t)kk * DIMX);
                wv[kk][0] = tmp.x; wv[kk][1] = tmp.y; wv[kk][2] = tmp.z; wv[kk][3] = tmp.w;
            }
#pragma unroll
            for (int t = 0; t < 4; ++t)
#pragma unroll
                for (int jj = 0; jj < 4; ++jj)
#pragma unroll
                    for (int kk = 0; kk < 4; ++kk)
                        acc[p][t][jj] += va[t][kk] * wv[kk][jj];
        }
    }
    __syncthreads();   // all v_s reads done; safe to overwrite with qkv

    // write q,k,vv rows (q region overlaps old v region — that's fine now)
#pragma unroll
    for (int p = 0; p < 3; ++p)
#pragma unroll
        for (int t = 0; t < 4; ++t) {
            float4 tmp = make_float4(acc[p][t][0], acc[p][t][1],
                                     acc[p][t][2], acc[p][t][3]);
            *(float4*)&smem[(t0 + t) * ROWSTRIDE + p * VSTRIDE + c0] = tmp;
        }
    __syncthreads();

    // ---------------- stage 2: per-token 8x8 softmax-attention ---------------
    // 16 threads per token: (h = sub>>1) row of attn, half of hd each.
    const int ta   = tid >> 4;        // token 0..15
    const int sub  = tid & 15;
    const int h    = sub >> 1;
    const int d0   = (sub & 1) * 16;  // which half of the 32-wide head dim
    const float scale = 0.17677669529663687f;  // 32^-0.5

    float qv[HDIM];
    {
        const float* qrow = &smem[ta * ROWSTRIDE + h * HDIM];
#pragma unroll
        for (int d = 0; d < HDIM; d += 4) {
            float4 tmp = *(const float4*)(qrow + d);
            qv[d] = tmp.x; qv[d+1] = tmp.y; qv[d+2] = tmp.z; qv[d+3] = tmp.w;
        }
    }

    float logits[NHEADS];
    const float* krows = &smem[ta * ROWSTRIDE + VSTRIDE];
#pragma unroll
    for (int g = 0; g < NHEADS; ++g) {
        const float* kr = krows + g * HDIM;
        float s = 0.f;
#pragma unroll
        for (int d = 0; d < HDIM; d += 4) {
            float4 tmp = *(const float4*)(kr + d);
            s += qv[d] * tmp.x + qv[d+1] * tmp.y + qv[d+2] * tmp.z + qv[d+3] * tmp.w;
        }
        logits[g] = s * scale;
    }
    float mx = logits[0];
#pragma unroll
    for (int g = 1; g < NHEADS; ++g) mx = fmaxf(mx, logits[g]);
    float se = 0.f;
#pragma unroll
    for (int g = 0; g < NHEADS; ++g) { logits[g] = expf(logits[g] - mx); se += logits[g]; }
    float inv = 1.f / se;
#pragma unroll
    for (int g = 0; g < NHEADS; ++g) logits[g] *= inv;

    float xacc[16];
#pragma unroll
    for (int d = 0; d < 16; ++d) xacc[d] = 0.f;
    const float* vrows = &smem[ta * ROWSTRIDE + 2 * VSTRIDE];
#pragma unroll
    for (int g = 0; g < NHEADS; ++g) {
        const float* vr = vrows + g * HDIM + d0;
        float pg = logits[g];
#pragma unroll
        for (int d = 0; d < 16; d += 4) {
            float4 tmp = *(const float4*)(vr + d);
            xacc[d]   += pg * tmp.x;
            xacc[d+1] += pg * tmp.y;
            xacc[d+2] += pg * tmp.z;
            xacc[d+3] += pg * tmp.w;
        }
    }
    __syncthreads();   // all q/k/vv reads done; safe to overwrite q with x
#pragma unroll
    for (int d = 0; d < 16; d += 4)
        *(float4*)&smem[ta * ROWSTRIDE + h * HDIM + d0 + d] =
            make_float4(xacc[d], xacc[d+1], xacc[d+2], xacc[d+3]);
    __syncthreads();

    // ---------------- stage 3: out = x @ Wp + bp -----------------------------
    float oacc[4][4];
#pragma unroll
    for (int t = 0; t < 4; ++t)
#pragma unroll
        for (int j = 0; j < 4; ++j)
            oacc[t][j] = 0.f;

    const float* Wpb = Wp + c0;
    for (int k = 0; k < DIMX; k += 4) {
        float xa[4][4];
#pragma unroll
        for (int t = 0; t < 4; ++t) {
            float4 tmp = *(const float4*)&smem[(t0 + t) * ROWSTRIDE + k];
            xa[t][0] = tmp.x; xa[t][1] = tmp.y; xa[t][2] = tmp.z; xa[t][3] = tmp.w;
        }
        float wv[4][4];
#pragma unroll
        for (int kk = 0; kk < 4; ++kk) {
            float4 tmp = *(const float4*)(Wpb + (size_t)(k + kk) * DIMX);
            wv[kk][0] = tmp.x; wv[kk][1] = tmp.y; wv[kk][2] = tmp.z; wv[kk][3] = tmp.w;
        }
#pragma unroll
        for (int t = 0; t < 4; ++t)
#pragma unroll
            for (int jj = 0; jj < 4; ++jj)
#pragma unroll
                for (int kk = 0; kk < 4; ++kk)
                    oacc[t][jj] += xa[t][kk] * wv[kk][jj];
    }

    float4 bias = *(const float4*)(bp + c0);
#pragma unroll
    for (int t = 0; t < 4; ++t) {
        float4 o = make_float4(oacc[t][0] + bias.x, oacc[t][1] + bias.y,
                               oacc[t][2] + bias.z, oacc[t][3] + bias.w);
        *(float4*)&out[(token0 + t0 + t) * DIMX + c0] = o;
    }
}

extern "C" void kernel_launch(void* const* d_in, const int* in_sizes, int n_in,
                              void* d_out, int out_size, void* d_ws, size_t ws_size,
                              hipStream_t stream) {
    const float* v  = (const float*)d_in[0];
    const float* Wq = (const float*)d_in[1];
    const float* Wk = (const float*)d_in[2];
    const float* Wv = (const float*)d_in[3];
    const float* Wp = (const float*)d_in[4];
    const float* bp = (const float*)d_in[5];
    float* out = (float*)d_out;

    const int ntokens = in_sizes[0] / DIMX;   // 65536
    dim3 grid(ntokens / TM);                  // 4096 workgroups
    fused_selfattn<<<grid, NTHREADS, 0, stream>>>(v, Wq, Wk, Wv, Wp, bp, out);
}

// Round 2
// 188.116 us; speedup vs baseline: 3.2051x; 3.2051x over previous
//
#include <hip/hip_runtime.h>
#include <hip/hip_bf16.h>
#include <math.h>

// Fused SelfAttention (attention over the HEADS axis, per token):
//   qkv = v @ [Wq|Wk|Wv]  (65536x256 @ 256x768, bf16 MFMA)
//   per-token 8x8 softmax attention over heads (fp32, cheap)
//   out = x @ Wp + bp       (65536x256 @ 256x256, bf16 MFMA)
//
// MFMA orientation trick: D = A*B with A = W^T-tile (rows = output col n),
// B = v^T-tile (cols = tokens). C/D layout (verified m89/m91):
//   col = lane&15  -> token
//   row = quad*4+r -> n (4 CONSECUTIVE output columns per lane)
// so qkv writeback is one ds_write_b64/tile and GEMM2 stores float4 to global.
// A-operand layout: A[m=lane&15][k=quad*8+j]  -> prep kernel packs W[k][n]
// into fragment order so the hot loop does coalesced 16B/lane global loads.

#define DIMX      256
#define NH        8
#define HD        32
#define TM        32       // tokens per block
#define NTHREADS  256
#define ASTRIDE   264      // bf16 units; 264*2=528 B rows (16B aligned)
#define QSTRIDE   776      // bf16 units; 776*2=1552 B rows (16B aligned)
#define NT_QKV    48       // 768/16 n-tiles in GEMM1
#define NT_P      16       // 256/16 n-tiles in GEMM2
#define KT        8        // 256/32 k-tiles

typedef __bf16 bf16x8 __attribute__((ext_vector_type(8)));
typedef __bf16 bf16x4 __attribute__((ext_vector_type(4)));
typedef float  f32x4  __attribute__((ext_vector_type(4)));

// ---------------------------------------------------------------------------
// Prep: pack Wq|Wk|Wv and Wp into MFMA A-operand fragment order, fp32->bf16.
// frag[j] = W[kt*32 + quad*8 + j][nt*16 + (lane&15)]
// packed index u = (nt*KT + kt)*64 + lane ; 8 bf16 (16 B) per u, contiguous.
// ---------------------------------------------------------------------------
__global__ void pack_weights(const float* __restrict__ Wq,
                             const float* __restrict__ Wk,
                             const float* __restrict__ Wv,
                             const float* __restrict__ Wp,
                             __bf16* __restrict__ pk)
{
    const int QKV_FRAGS = NT_QKV * KT * 64;   // 24576
    int u = blockIdx.x * blockDim.x + threadIdx.x;  // 0..32767
    const float* W;
    int nt, kt, lane;
    if (u < QKV_FRAGS) {
        nt = u / (KT * 64); kt = (u / 64) % KT; lane = u % 64;
        if (nt < 16)      { W = Wq; }
        else if (nt < 32) { W = Wk; nt -= 16; }
        else              { W = Wv; nt -= 32; }
    } else {
        int u2 = u - QKV_FRAGS;
        nt = u2 / (KT * 64); kt = (u2 / 64) % KT; lane = u2 % 64;
        W = Wp;
    }
    const int n  = nt * 16 + (lane & 15);
    const int k0 = kt * 32 + (lane >> 4) * 8;
    bf16x8 frag;
#pragma unroll
    for (int j = 0; j < 8; ++j)
        frag[j] = (__bf16)W[(size_t)(k0 + j) * DIMX + n];
    *(bf16x8*)(pk + (size_t)u * 8) = frag;
}

// ---------------------------------------------------------------------------
// Main fused kernel. LDS: As (32x264 bf16, v-tile then x-tile) + QKV (32x776).
// ---------------------------------------------------------------------------
__global__ __launch_bounds__(NTHREADS, 2)
void fused_attn_mfma(const float* __restrict__ v,
                     const __bf16* __restrict__ Wqkv_pk,
                     const __bf16* __restrict__ Wp_pk,
                     const float* __restrict__ bp,
                     float* __restrict__ out)
{
    __shared__ __align__(16) unsigned short smem[TM * ASTRIDE + TM * QSTRIDE];
    unsigned short* As  = smem;                 // v tile, later x tile
    unsigned short* QKV = smem + TM * ASTRIDE;  // q[0:256) k[256:512) vv[512:768)

    const int tid   = threadIdx.x;
    const int lane  = tid & 63;
    const int wv_id = tid >> 6;      // wave 0..3
    const int l15   = lane & 15;
    const int quad  = lane >> 4;
    const long token0 = (long)blockIdx.x * TM;

    // ---- stage 0: v tile fp32 -> bf16 -> As (row-major, stride 264) --------
    {
        const float4* src = (const float4*)(v + token0 * DIMX);
#pragma unroll
        for (int i = 0; i < 8; ++i) {
            int u = tid + NTHREADS * i;       // 0..2047 float4 slots
            int m = u >> 6;                   // token row
            int c = (u & 63) * 4;             // col
            float4 t4 = src[u];
            bf16x4 b4 = { (__bf16)t4.x, (__bf16)t4.y, (__bf16)t4.z, (__bf16)t4.w };
            *(bf16x4*)&As[m * ASTRIDE + c] = b4;
        }
    }
    __syncthreads();

    // ---- GEMM1: qkv^T tiles; wave w owns n-tiles [w*12, w*12+12) -----------
    {
        const int nt0 = wv_id * 12;
        f32x4 acc[2][12];
#pragma unroll
        for (int tt = 0; tt < 2; ++tt)
#pragma unroll
            for (int j = 0; j < 12; ++j)
                acc[tt][j] = (f32x4){0.f, 0.f, 0.f, 0.f};

        for (int kt = 0; kt < KT; ++kt) {
            bf16x8 vf[2];
#pragma unroll
            for (int tt = 0; tt < 2; ++tt)
                vf[tt] = *(const bf16x8*)&As[(tt * 16 + l15) * ASTRIDE + kt * 32 + quad * 8];
            const bf16x8* wb = (const bf16x8*)Wqkv_pk + ((size_t)(nt0 * KT + kt) * 64 + lane);
#pragma unroll
            for (int j = 0; j < 12; ++j) {
                bf16x8 wf = wb[(size_t)j * KT * 64];
                acc[0][j] = __builtin_amdgcn_mfma_f32_16x16x32_bf16(wf, vf[0], acc[0][j], 0, 0, 0);
                acc[1][j] = __builtin_amdgcn_mfma_f32_16x16x32_bf16(wf, vf[1], acc[1][j], 0, 0, 0);
            }
        }
        // writeback: token = l15 (+16*tt), n = (nt0+j)*16 + quad*4 + r
#pragma unroll
        for (int tt = 0; tt < 2; ++tt)
#pragma unroll
            for (int j = 0; j < 12; ++j) {
                bf16x4 p4 = { (__bf16)acc[tt][j][0], (__bf16)acc[tt][j][1],
                              (__bf16)acc[tt][j][2], (__bf16)acc[tt][j][3] };
                *(bf16x4*)&QKV[(tt * 16 + l15) * QSTRIDE + (nt0 + j) * 16 + quad * 4] = p4;
            }
    }
    __syncthreads();

    // ---- attention: 8 threads/token, thread = (token ta, head h) -----------
    {
        const int ta = tid >> 3;
        const int h  = tid & 7;
        const float scale = 0.17677669529663687f;  // 32^-0.5
        const unsigned short* qrow = &QKV[ta * QSTRIDE + h * HD];
        const unsigned short* kbase = &QKV[ta * QSTRIDE + 256];
        const unsigned short* vbase = &QKV[ta * QSTRIDE + 512];

        float q[HD];
#pragma unroll
        for (int s = 0; s < 4; ++s) {
            bf16x8 t = *(const bf16x8*)(qrow + s * 8);
#pragma unroll
            for (int j = 0; j < 8; ++j) q[s * 8 + j] = (float)t[j];
        }
        float logits[NH];
#pragma unroll
        for (int g = 0; g < NH; ++g) {
            float s = 0.f;
#pragma unroll
            for (int sg = 0; sg < 4; ++sg) {
                bf16x8 t = *(const bf16x8*)(kbase + g * HD + sg * 8);
#pragma unroll
                for (int j = 0; j < 8; ++j) s += q[sg * 8 + j] * (float)t[j];
            }
            logits[g] = s * scale;
        }
        float mx = logits[0];
#pragma unroll
        for (int g = 1; g < NH; ++g) mx = fmaxf(mx, logits[g]);
        float se = 0.f;
#pragma unroll
        for (int g = 0; g < NH; ++g) { logits[g] = __expf(logits[g] - mx); se += logits[g]; }
        float inv = 1.f / se;
#pragma unroll
        for (int g = 0; g < NH; ++g) logits[g] *= inv;

        float x[HD];
#pragma unroll
        for (int d = 0; d < HD; ++d) x[d] = 0.f;
#pragma unroll
        for (int g = 0; g < NH; ++g) {
            float p = logits[g];
#pragma unroll
            for (int sg = 0; sg < 4; ++sg) {
                bf16x8 t = *(const bf16x8*)(vbase + g * HD + sg * 8);
#pragma unroll
                for (int j = 0; j < 8; ++j) x[sg * 8 + j] += p * (float)t[j];
            }
        }
        // write x row (bf16) into Xs (= As region; all As reads finished)
#pragma unroll
        for (int s = 0; s < 4; ++s) {
            bf16x8 o;
#pragma unroll
            for (int j = 0; j < 8; ++j) o[j] = (__bf16)x[s * 8 + j];
            *(bf16x8*)&As[ta * ASTRIDE + h * HD + s * 8] = o;
        }
    }
    __syncthreads();

    // ---- GEMM2: out = x @ Wp + bp; wave w owns n-tiles [w*4, w*4+4) --------
    {
        const int nt0 = wv_id * 4;
        f32x4 acc[2][4];
#pragma unroll
        for (int tt = 0; tt < 2; ++tt)
#pragma unroll
            for (int j = 0; j < 4; ++j)
                acc[tt][j] = (f32x4){0.f, 0.f, 0.f, 0.f};

        for (int kt = 0; kt < KT; ++kt) {
            bf16x8 xf[2];
#pragma unroll
            for (int tt = 0; tt < 2; ++tt)
                xf[tt] = *(const bf16x8*)&As[(tt * 16 + l15) * ASTRIDE + kt * 32 + quad * 8];
            const bf16x8* wb = (const bf16x8*)Wp_pk + ((size_t)(nt0 * KT + kt) * 64 + lane);
#pragma unroll
            for (int j = 0; j < 4; ++j) {
                bf16x8 wf = wb[(size_t)j * KT * 64];
                acc[0][j] = __builtin_amdgcn_mfma_f32_16x16x32_bf16(wf, xf[0], acc[0][j], 0, 0, 0);
                acc[1][j] = __builtin_amdgcn_mfma_f32_16x16x32_bf16(wf, xf[1], acc[1][j], 0, 0, 0);
            }
        }
        // bias + store: out[token][ (nt0+j)*16 + quad*4 .. +3 ] as float4
#pragma unroll
        for (int j = 0; j < 4; ++j) {
            f32x4 b = *(const f32x4*)&bp[(nt0 + j) * 16 + quad * 4];
#pragma unroll
            for (int tt = 0; tt < 2; ++tt) {
                f32x4 o = acc[tt][j] + b;
                *(f32x4*)&out[(token0 + tt * 16 + l15) * DIMX + (nt0 + j) * 16 + quad * 4] = o;
            }
        }
    }
}

extern "C" void kernel_launch(void* const* d_in, const int* in_sizes, int n_in,
                              void* d_out, int out_size, void* d_ws, size_t ws_size,
                              hipStream_t stream) {
    const float* v  = (const float*)d_in[0];
    const float* Wq = (const float*)d_in[1];
    const float* Wk = (const float*)d_in[2];
    const float* Wv = (const float*)d_in[3];
    const float* Wp = (const float*)d_in[4];
    const float* bp = (const float*)d_in[5];
    float* out = (float*)d_out;

    __bf16* pk = (__bf16*)d_ws;                    // 32768 frags * 16 B = 512 KB
    const __bf16* Wqkv_pk = pk;                    // 24576 frags
    const __bf16* Wp_pk   = pk + (size_t)24576 * 8;

    pack_weights<<<128, 256, 0, stream>>>(Wq, Wk, Wv, Wp, pk);

    const int ntokens = in_sizes[0] / DIMX;        // 65536
    fused_attn_mfma<<<ntokens / TM, NTHREADS, 0, stream>>>(v, Wqkv_pk, Wp_pk, bp, out);
}

// Round 3
// 163.884 us; speedup vs baseline: 3.6790x; 1.1479x over previous
//
#include <hip/hip_runtime.h>
#include <hip/hip_bf16.h>
#include <math.h>

// Fused SelfAttention (attention over the HEADS axis, per token):
//   qkv = v @ [Wq|Wk|Wv]  (65536x256 @ 256x768, bf16 MFMA)
//   per-token 8x8 softmax attention over heads (fp32, cheap)
//   out = x @ Wp + bp       (65536x256 @ 256x256, bf16 MFMA)
//
// MFMA orientation: D = A*B, A = W^T-tile (rows = output col n), B = v^T-tile
// (cols = tokens). C/D layout: col(lane&15)=token, row(quad*4+r)=n -> 4
// consecutive output columns per lane => ds_write_b64 qkv writeback, float4
// global stores in GEMM2. A-frags packed by prep kernel (coalesced 16B/lane).
//
// R3 changes vs R2: 512-thread blocks (8 waves) at same TM=32 / same LDS
// -> 16 waves/CU (2 blocks/CU); explicit register double-buffer of weight
// frags to hide L2 latency; attention split 16 threads/token with shfl_xor.

#define DIMX      256
#define NH        8
#define HD        32
#define TM        32       // tokens per block
#define NTHREADS  512      // 8 waves
#define ASTRIDE   264      // bf16 units; 528 B rows (16B aligned, 2-way banks)
#define QSTRIDE   776      // bf16 units; 1552 B rows
#define NT_QKV    48       // 768/16 n-tiles in GEMM1
#define KT        8        // 256/32 k-tiles
#define NJ1       6        // n-tiles per wave, GEMM1 (8 waves * 6 = 48)
#define NJ2       2        // n-tiles per wave, GEMM2 (8 waves * 2 = 16)

typedef __bf16 bf16x8 __attribute__((ext_vector_type(8)));
typedef __bf16 bf16x4 __attribute__((ext_vector_type(4)));
typedef float  f32x4  __attribute__((ext_vector_type(4)));

// ---------------------------------------------------------------------------
// Prep: pack Wq|Wk|Wv and Wp into MFMA A-operand fragment order, fp32->bf16.
// frag[j] = W[kt*32 + quad*8 + j][nt*16 + (lane&15)]
// packed index u = (nt*KT + kt)*64 + lane ; 8 bf16 (16 B) per u, contiguous.
// ---------------------------------------------------------------------------
__global__ void pack_weights(const float* __restrict__ Wq,
                             const float* __restrict__ Wk,
                             const float* __restrict__ Wv,
                             const float* __restrict__ Wp,
                             __bf16* __restrict__ pk)
{
    const int QKV_FRAGS = NT_QKV * KT * 64;   // 24576
    int u = blockIdx.x * blockDim.x + threadIdx.x;  // 0..32767
    const float* W;
    int nt, kt, lane;
    if (u < QKV_FRAGS) {
        nt = u / (KT * 64); kt = (u / 64) % KT; lane = u % 64;
        if (nt < 16)      { W = Wq; }
        else if (nt < 32) { W = Wk; nt -= 16; }
        else              { W = Wv; nt -= 32; }
    } else {
        int u2 = u - QKV_FRAGS;
        nt = u2 / (KT * 64); kt = (u2 / 64) % KT; lane = u2 % 64;
        W = Wp;
    }
    const int n  = nt * 16 + (lane & 15);
    const int k0 = kt * 32 + (lane >> 4) * 8;
    bf16x8 frag;
#pragma unroll
    for (int j = 0; j < 8; ++j)
        frag[j] = (__bf16)W[(size_t)(k0 + j) * DIMX + n];
    *(bf16x8*)(pk + (size_t)u * 8) = frag;
}

// ---------------------------------------------------------------------------
// Main fused kernel. LDS: As (32x264 bf16, v tile then x tile) + QKV (32x776).
// ---------------------------------------------------------------------------
__global__ __launch_bounds__(NTHREADS, 4)   // 4 waves/EU -> VGPR<=128, 2 blk/CU
void fused_attn_mfma(const float* __restrict__ v,
                     const __bf16* __restrict__ Wqkv_pk,
                     const __bf16* __restrict__ Wp_pk,
                     const float* __restrict__ bp,
                     float* __restrict__ out)
{
    __shared__ __align__(16) unsigned short smem[TM * ASTRIDE + TM * QSTRIDE];
    unsigned short* As  = smem;                 // v tile, later x tile
    unsigned short* QKV = smem + TM * ASTRIDE;  // q[0:256) k[256:512) vv[512:768)

    const int tid   = threadIdx.x;
    const int lane  = tid & 63;
    const int wv_id = tid >> 6;      // wave 0..7
    const int l15   = lane & 15;
    const int quad  = lane >> 4;
    const long token0 = (long)blockIdx.x * TM;

    // ---- stage 0: v tile fp32 -> bf16 -> As (row-major, stride 264) --------
    {
        const float4* src = (const float4*)(v + token0 * DIMX);
#pragma unroll
        for (int i = 0; i < 4; ++i) {
            int u = tid + NTHREADS * i;       // 0..2047 float4 slots
            int m = u >> 6;                   // token row
            int c = (u & 63) * 4;             // col
            float4 t4 = src[u];
            bf16x4 b4 = { (__bf16)t4.x, (__bf16)t4.y, (__bf16)t4.z, (__bf16)t4.w };
            *(bf16x4*)&As[m * ASTRIDE + c] = b4;
        }
    }
    __syncthreads();

    // ---- GEMM1: qkv^T tiles; wave w owns n-tiles [w*6, w*6+6) --------------
    {
        const int nt0 = wv_id * NJ1;
        f32x4 acc[2][NJ1];
#pragma unroll
        for (int tt = 0; tt < 2; ++tt)
#pragma unroll
            for (int j = 0; j < NJ1; ++j)
                acc[tt][j] = (f32x4){0.f, 0.f, 0.f, 0.f};

        const bf16x8* wb = (const bf16x8*)Wqkv_pk + lane;
        bf16x8 wcur[NJ1];
#pragma unroll
        for (int j = 0; j < NJ1; ++j)
            wcur[j] = wb[(size_t)((nt0 + j) * KT) * 64];

        for (int kt = 0; kt < KT; ++kt) {
            const int ktn = (kt + 1 < KT) ? kt + 1 : KT - 1;
            bf16x8 wnxt[NJ1];
#pragma unroll
            for (int j = 0; j < NJ1; ++j)
                wnxt[j] = wb[(size_t)((nt0 + j) * KT + ktn) * 64];

            bf16x8 vf[2];
#pragma unroll
            for (int tt = 0; tt < 2; ++tt)
                vf[tt] = *(const bf16x8*)&As[(tt * 16 + l15) * ASTRIDE + kt * 32 + quad * 8];

#pragma unroll
            for (int j = 0; j < NJ1; ++j) {
                acc[0][j] = __builtin_amdgcn_mfma_f32_16x16x32_bf16(wcur[j], vf[0], acc[0][j], 0, 0, 0);
                acc[1][j] = __builtin_amdgcn_mfma_f32_16x16x32_bf16(wcur[j], vf[1], acc[1][j], 0, 0, 0);
            }
#pragma unroll
            for (int j = 0; j < NJ1; ++j) wcur[j] = wnxt[j];
        }
        // writeback: token = tt*16+l15, n = (nt0+j)*16 + quad*4 + r
#pragma unroll
        for (int tt = 0; tt < 2; ++tt)
#pragma unroll
            for (int j = 0; j < NJ1; ++j) {
                bf16x4 p4 = { (__bf16)acc[tt][j][0], (__bf16)acc[tt][j][1],
                              (__bf16)acc[tt][j][2], (__bf16)acc[tt][j][3] };
                *(bf16x4*)&QKV[(tt * 16 + l15) * QSTRIDE + (nt0 + j) * 16 + quad * 4] = p4;
            }
    }
    __syncthreads();

    // ---- attention: 16 threads/token = (head h, half d0); shfl_xor combine --
    {
        const int ta  = tid >> 4;         // token 0..31
        const int sub = tid & 15;
        const int h   = sub >> 1;
        const int d0  = (sub & 1) * 16;   // half of the 32-wide head dim
        const float scale = 0.17677669529663687f;  // 32^-0.5

        const unsigned short* qrow  = &QKV[ta * QSTRIDE + h * HD + d0];
        const unsigned short* kbase = &QKV[ta * QSTRIDE + 256 + d0];
        const unsigned short* vbase = &QKV[ta * QSTRIDE + 512 + d0];

        float q[16];
#pragma unroll
        for (int s = 0; s < 2; ++s) {
            bf16x8 t = *(const bf16x8*)(qrow + s * 8);
#pragma unroll
            for (int j = 0; j < 8; ++j) q[s * 8 + j] = (float)t[j];
        }
        float logits[NH];
#pragma unroll
        for (int g = 0; g < NH; ++g) {
            float s = 0.f;
#pragma unroll
            for (int sg = 0; sg < 2; ++sg) {
                bf16x8 t = *(const bf16x8*)(kbase + g * HD + sg * 8);
#pragma unroll
                for (int j = 0; j < 8; ++j) s += q[sg * 8 + j] * (float)t[j];
            }
            logits[g] = s;
        }
        // combine the two half-dim partials (partner lane = tid^1)
#pragma unroll
        for (int g = 0; g < NH; ++g)
            logits[g] = (logits[g] + __shfl_xor(logits[g], 1, 64)) * scale;

        float mx = logits[0];
#pragma unroll
        for (int g = 1; g < NH; ++g) mx = fmaxf(mx, logits[g]);
        float se = 0.f;
#pragma unroll
        for (int g = 0; g < NH; ++g) { logits[g] = __expf(logits[g] - mx); se += logits[g]; }
        float inv = 1.f / se;
#pragma unroll
        for (int g = 0; g < NH; ++g) logits[g] *= inv;

        float x[16];
#pragma unroll
        for (int d = 0; d < 16; ++d) x[d] = 0.f;
#pragma unroll
        for (int g = 0; g < NH; ++g) {
            float p = logits[g];
#pragma unroll
            for (int sg = 0; sg < 2; ++sg) {
                bf16x8 t = *(const bf16x8*)(vbase + g * HD + sg * 8);
#pragma unroll
                for (int j = 0; j < 8; ++j) x[sg * 8 + j] += p * (float)t[j];
            }
        }
        __syncthreads();   // all As (v tile) reads finished in GEMM1
#pragma unroll
        for (int s = 0; s < 2; ++s) {
            bf16x8 o;
#pragma unroll
            for (int j = 0; j < 8; ++j) o[j] = (__bf16)x[s * 8 + j];
            *(bf16x8*)&As[ta * ASTRIDE + h * HD + d0 + s * 8] = o;
        }
    }
    __syncthreads();

    // ---- GEMM2: out = x @ Wp + bp; wave w owns n-tiles [w*2, w*2+2) --------
    {
        const int nt0 = wv_id * NJ2;
        f32x4 acc[2][NJ2];
#pragma unroll
        for (int tt = 0; tt < 2; ++tt)
#pragma unroll
            for (int j = 0; j < NJ2; ++j)
                acc[tt][j] = (f32x4){0.f, 0.f, 0.f, 0.f};

        const bf16x8* wb = (const bf16x8*)Wp_pk + lane;
        bf16x8 wcur[NJ2];
#pragma unroll
        for (int j = 0; j < NJ2; ++j)
            wcur[j] = wb[(size_t)((nt0 + j) * KT) * 64];

        for (int kt = 0; kt < KT; ++kt) {
            const int ktn = (kt + 1 < KT) ? kt + 1 : KT - 1;
            bf16x8 wnxt[NJ2];
#pragma unroll
            for (int j = 0; j < NJ2; ++j)
                wnxt[j] = wb[(size_t)((nt0 + j) * KT + ktn) * 64];

            bf16x8 xf[2];
#pragma unroll
            for (int tt = 0; tt < 2; ++tt)
                xf[tt] = *(const bf16x8*)&As[(tt * 16 + l15) * ASTRIDE + kt * 32 + quad * 8];

#pragma unroll
            for (int j = 0; j < NJ2; ++j) {
                acc[0][j] = __builtin_amdgcn_mfma_f32_16x16x32_bf16(wcur[j], xf[0], acc[0][j], 0, 0, 0);
                acc[1][j] = __builtin_amdgcn_mfma_f32_16x16x32_bf16(wcur[j], xf[1], acc[1][j], 0, 0, 0);
            }
#pragma unroll
            for (int j = 0; j < NJ2; ++j) wcur[j] = wnxt[j];
        }
        // bias + store: out[token][ (nt0+j)*16 + quad*4 .. +3 ] as float4
#pragma unroll
        for (int j = 0; j < NJ2; ++j) {
            f32x4 b = *(const f32x4*)&bp[(nt0 + j) * 16 + quad * 4];
#pragma unroll
            for (int tt = 0; tt < 2; ++tt) {
                f32x4 o = acc[tt][j] + b;
                *(f32x4*)&out[(token0 + tt * 16 + l15) * DIMX + (nt0 + j) * 16 + quad * 4] = o;
            }
        }
    }
}

extern "C" void kernel_launch(void* const* d_in, const int* in_sizes, int n_in,
                              void* d_out, int out_size, void* d_ws, size_t ws_size,
                              hipStream_t stream) {
    const float* v  = (const float*)d_in[0];
    const float* Wq = (const float*)d_in[1];
    const float* Wk = (const float*)d_in[2];
    const float* Wv = (const float*)d_in[3];
    const float* Wp = (const float*)d_in[4];
    const float* bp = (const float*)d_in[5];
    float* out = (float*)d_out;

    __bf16* pk = (__bf16*)d_ws;                    // 32768 frags * 16 B = 512 KB
    const __bf16* Wqkv_pk = pk;                    // 24576 frags
    const __bf16* Wp_pk   = pk + (size_t)24576 * 8;

    pack_weights<<<256, 128, 0, stream>>>(Wq, Wk, Wv, Wp, pk);

    const int ntokens = in_sizes[0] / DIMX;        // 65536
    fused_attn_mfma<<<ntokens / TM, NTHREADS, 0, stream>>>(v, Wqkv_pk, Wp_pk, bp, out);
}

// Round 4
// 158.713 us; speedup vs baseline: 3.7989x; 1.0326x over previous
//
#include <hip/hip_runtime.h>
#include <hip/hip_bf16.h>
#include <math.h>

// Fused SelfAttention (attention over the HEADS axis, per token):
//   qkv = v @ [Wq|Wk|Wv]  (65536x256 @ 256x768, f16 MFMA)
//   per-token 8x8 softmax attention over heads (packed f16 + fp32 softmax)
//   out = x @ Wp + bp       (65536x256 @ 256x256, f16 MFMA)
//
// MFMA orientation: D = A*B, A = W^T-tile (rows = output col n), B = v^T-tile
// (cols = tokens). C/D layout: col(lane&15)=token, row(quad*4+r)=n.
// R4: f16 everywhere (pk_fma attention), LDS 48.5 KB via v-tile/QKV aliasing
// (v tile lives in the q-section cols [0,256) and is overwritten post-barrier),
// GEMM1 in two 3-tile passes for <=85 VGPR -> 3 blocks/CU, 24 waves/CU.

#define DIMX      256
#define NH        8
#define HD        32
#define TM        32       // tokens per block
#define NTHREADS  512      // 8 waves
#define QSTRIDE   776      // f16 units per row; 1552 B (16B aligned, banks ok)
#define KT        8        // 256/32 k-tiles
#define NT_QKV    48       // q: 0..15, k: 16..31, v: 32..47

typedef _Float16 f16x8 __attribute__((ext_vector_type(8)));
typedef _Float16 f16x4 __attribute__((ext_vector_type(4)));
typedef _Float16 f16x2 __attribute__((ext_vector_type(2)));
typedef float    f32x4 __attribute__((ext_vector_type(4)));

static __device__ __forceinline__ f16x2 pkrtz(float a, float b) {
    return (f16x2)__builtin_amdgcn_cvt_pkrtz(a, b);
}

// ---------------------------------------------------------------------------
// Prep: pack Wq|Wk|Wv and Wp into MFMA A-operand fragment order, fp32->f16.
// frag[j] = W[kt*32 + quad*8 + j][nt*16 + (lane&15)]
// packed index u = (nt*KT + kt)*64 + lane ; 8 f16 (16 B) per u, contiguous.
// ---------------------------------------------------------------------------
__global__ void pack_weights(const float* __restrict__ Wq,
                             const float* __restrict__ Wk,
                             const float* __restrict__ Wv,
                             const float* __restrict__ Wp,
                             _Float16* __restrict__ pk)
{
    const int QKV_FRAGS = NT_QKV * KT * 64;   // 24576
    int u = blockIdx.x * blockDim.x + threadIdx.x;  // 0..32767
    const float* W;
    int nt, kt, lane;
    if (u < QKV_FRAGS) {
        nt = u / (KT * 64); kt = (u / 64) % KT; lane = u % 64;
        if (nt < 16)      { W = Wq; }
        else if (nt < 32) { W = Wk; nt -= 16; }
        else              { W = Wv; nt -= 32; }
    } else {
        int u2 = u - QKV_FRAGS;
        nt = u2 / (KT * 64); kt = (u2 / 64) % KT; lane = u2 % 64;
        W = Wp;
    }
    const int n  = nt * 16 + (lane & 15);
    const int k0 = kt * 32 + (lane >> 4) * 8;
    f16x8 frag;
#pragma unroll
    for (int j = 0; j < 8; ++j)
        frag[j] = (_Float16)W[(size_t)(k0 + j) * DIMX + n];
    *(f16x8*)(pk + (size_t)u * 8) = frag;
}

// ---------------------------------------------------------------------------
// Main fused kernel. LDS: single 32x776 f16 region.
//   phase A: v tile in cols [0,256); phase B: q|k|vv in cols [0,768);
//   phase C: x tile overwrites q-section cols [0,256).
// ---------------------------------------------------------------------------
__global__ __launch_bounds__(NTHREADS, 6)   // 6 waves/EU -> 3 blocks/CU
void fused_attn_mfma(const float* __restrict__ v,
                     const _Float16* __restrict__ Wqkv_pk,
                     const _Float16* __restrict__ Wp_pk,
                     const float* __restrict__ bp,
                     float* __restrict__ out)
{
    __shared__ __align__(16) _Float16 S[TM * QSTRIDE];   // 49664 B

    const int tid   = threadIdx.x;
    const int lane  = tid & 63;
    const int wv_id = tid >> 6;      // wave 0..7
    const int l15   = lane & 15;
    const int quad  = lane >> 4;
    const long token0 = (long)blockIdx.x * TM;

    // ---- stage 0: v tile fp32 -> f16 -> S cols [0,256) ---------------------
    {
        const float4* src = (const float4*)(v + token0 * DIMX);
#pragma unroll
        for (int i = 0; i < 4; ++i) {
            int u = tid + NTHREADS * i;       // 0..2047 float4 slots
            int m = u >> 6;                   // token row (wave-uniform)
            int c = (u & 63) * 4;
            float4 t4 = src[u];
            f16x2 lo = pkrtz(t4.x, t4.y), hi = pkrtz(t4.z, t4.w);
            f16x4 b4 = { lo.x, lo.y, hi.x, hi.y };
            *(f16x4*)&S[m * QSTRIDE + c] = b4;
        }
    }
    __syncthreads();

    // ---- GEMM1: two passes of 3 n-tiles per wave ---------------------------
    // pass0 tiles: 16 + wv*3 + i  (k-section + low v-section; no alias with
    //   the v-tile cols [0,256)) -> immediate writeback.
    // pass1 tiles: {2wv, 2wv+1, 40+wv} (q-section + v-tail) -> writeback
    //   deferred until after the all-reads-done barrier.
    f32x4 acc1[2][3];
    int tiles1[3] = { 2 * wv_id, 2 * wv_id + 1, 40 + wv_id };
    {
        int tiles0[3] = { 16 + wv_id * 3, 17 + wv_id * 3, 18 + wv_id * 3 };

        // ---------- pass 0 ----------
        f32x4 acc0[2][3];
#pragma unroll
        for (int tt = 0; tt < 2; ++tt)
#pragma unroll
            for (int j = 0; j < 3; ++j)
                acc0[tt][j] = (f32x4){0.f, 0.f, 0.f, 0.f};
        {
            const f16x8* wb = (const f16x8*)Wqkv_pk + lane;
            f16x8 wcur[3];
#pragma unroll
            for (int j = 0; j < 3; ++j)
                wcur[j] = wb[(size_t)(tiles0[j] * KT) * 64];
            for (int kt = 0; kt < KT; ++kt) {
                const int ktn = (kt + 1 < KT) ? kt + 1 : KT - 1;
                f16x8 wnxt[3];
#pragma unroll
                for (int j = 0; j < 3; ++j)
                    wnxt[j] = wb[(size_t)(tiles0[j] * KT + ktn) * 64];
                f16x8 vf[2];
#pragma unroll
                for (int tt = 0; tt < 2; ++tt)
                    vf[tt] = *(const f16x8*)&S[(tt * 16 + l15) * QSTRIDE + kt * 32 + quad * 8];
#pragma unroll
                for (int j = 0; j < 3; ++j) {
                    acc0[0][j] = __builtin_amdgcn_mfma_f32_16x16x32_f16(wcur[j], vf[0], acc0[0][j], 0, 0, 0);
                    acc0[1][j] = __builtin_amdgcn_mfma_f32_16x16x32_f16(wcur[j], vf[1], acc0[1][j], 0, 0, 0);
                }
#pragma unroll
                for (int j = 0; j < 3; ++j) wcur[j] = wnxt[j];
            }
        }
        // immediate writeback (cols >= 256; no alias with v tile)
#pragma unroll
        for (int tt = 0; tt < 2; ++tt)
#pragma unroll
            for (int j = 0; j < 3; ++j) {
                f16x2 a = pkrtz(acc0[tt][j][0], acc0[tt][j][1]);
                f16x2 b = pkrtz(acc0[tt][j][2], acc0[tt][j][3]);
                f16x4 p4 = { a.x, a.y, b.x, b.y };
                *(f16x4*)&S[(tt * 16 + l15) * QSTRIDE + tiles0[j] * 16 + quad * 4] = p4;
            }

        // ---------- pass 1 ----------
#pragma unroll
        for (int tt = 0; tt < 2; ++tt)
#pragma unroll
            for (int j = 0; j < 3; ++j)
                acc1[tt][j] = (f32x4){0.f, 0.f, 0.f, 0.f};
        {
            const f16x8* wb = (const f16x8*)Wqkv_pk + lane;
            f16x8 wcur[3];
#pragma unroll
            for (int j = 0; j < 3; ++j)
                wcur[j] = wb[(size_t)(tiles1[j] * KT) * 64];
            for (int kt = 0; kt < KT; ++kt) {
                const int ktn = (kt + 1 < KT) ? kt + 1 : KT - 1;
                f16x8 wnxt[3];
#pragma unroll
                for (int j = 0; j < 3; ++j)
                    wnxt[j] = wb[(size_t)(tiles1[j] * KT + ktn) * 64];
                f16x8 vf[2];
#pragma unroll
                for (int tt = 0; tt < 2; ++tt)
                    vf[tt] = *(const f16x8*)&S[(tt * 16 + l15) * QSTRIDE + kt * 32 + quad * 8];
#pragma unroll
                for (int j = 0; j < 3; ++j) {
                    acc1[0][j] = __builtin_amdgcn_mfma_f32_16x16x32_f16(wcur[j], vf[0], acc1[0][j], 0, 0, 0);
                    acc1[1][j] = __builtin_amdgcn_mfma_f32_16x16x32_f16(wcur[j], vf[1], acc1[1][j], 0, 0, 0);
                }
#pragma unroll
                for (int j = 0; j < 3; ++j) wcur[j] = wnxt[j];
            }
        }
    }
    __syncthreads();   // ALL v-tile reads done; q-section may now be written

#pragma unroll
    for (int tt = 0; tt < 2; ++tt)
#pragma unroll
        for (int j = 0; j < 3; ++j) {
            f16x2 a = pkrtz(acc1[tt][j][0], acc1[tt][j][1]);
            f16x2 b = pkrtz(acc1[tt][j][2], acc1[tt][j][3]);
            f16x4 p4 = { a.x, a.y, b.x, b.y };
            *(f16x4*)&S[(tt * 16 + l15) * QSTRIDE + tiles1[j] * 16 + quad * 4] = p4;
        }
    __syncthreads();

    // ---- attention: 16 threads/token = (head h, half d0); packed f16 -------
    {
        const int ta  = tid >> 4;         // token 0..31
        const int sub = tid & 15;
        const int h   = sub >> 1;
        const int d0  = (sub & 1) * 16;   // half of the 32-wide head dim
        const float scale = 0.17677669529663687f;  // 32^-0.5

        const _Float16* qrow  = &S[ta * QSTRIDE + h * HD + d0];
        const _Float16* kbase = &S[ta * QSTRIDE + 256 + d0];
        const _Float16* vbase = &S[ta * QSTRIDE + 512 + d0];

        f16x8 q0 = *(const f16x8*)qrow;
        f16x8 q1 = *(const f16x8*)(qrow + 8);

        float logits[NH];
#pragma unroll
        for (int g = 0; g < NH; ++g) {
            f16x8 k0 = *(const f16x8*)(kbase + g * HD);
            f16x8 k1 = *(const f16x8*)(kbase + g * HD + 8);
            f16x8 p  = q0 * k0;
            p += q1 * k1;
            f16x4 r4 = __builtin_shufflevector(p, p, 0, 1, 2, 3)
                     + __builtin_shufflevector(p, p, 4, 5, 6, 7);
            f16x2 r2 = __builtin_shufflevector(r4, r4, 0, 1)
                     + __builtin_shufflevector(r4, r4, 2, 3);
            logits[g] = (float)r2.x + (float)r2.y;
        }
#pragma unroll
        for (int g = 0; g < NH; ++g)
            logits[g] = (logits[g] + __shfl_xor(logits[g], 1, 64)) * scale;

        float mx = logits[0];
#pragma unroll
        for (int g = 1; g < NH; ++g) mx = fmaxf(mx, logits[g]);
        float se = 0.f;
#pragma unroll
        for (int g = 0; g < NH; ++g) { logits[g] = __expf(logits[g] - mx); se += logits[g]; }
        float inv = 1.f / se;

        f16x8 xa0 = (f16x8)(_Float16)0.f;
        f16x8 xa1 = (f16x8)(_Float16)0.f;
#pragma unroll
        for (int g = 0; g < NH; ++g) {
            _Float16 ph = (_Float16)(logits[g] * inv);
            f16x8 pw = { ph, ph, ph, ph, ph, ph, ph, ph };
            f16x8 v0 = *(const f16x8*)(vbase + g * HD);
            f16x8 v1 = *(const f16x8*)(vbase + g * HD + 8);
            xa0 += pw * v0;
            xa1 += pw * v1;
        }
        __syncthreads();   // all q/k reads done; safe to overwrite q with x
        *(f16x8*)&S[ta * QSTRIDE + h * HD + d0]     = xa0;
        *(f16x8*)&S[ta * QSTRIDE + h * HD + d0 + 8] = xa1;
    }
    __syncthreads();

    // ---- GEMM2: out = x @ Wp + bp; wave w owns n-tiles {2w, 2w+1} ----------
    {
        const int nt0 = wv_id * 2;
        f32x4 acc[2][2];
#pragma unroll
        for (int tt = 0; tt < 2; ++tt)
#pragma unroll
            for (int j = 0; j < 2; ++j)
                acc[tt][j] = (f32x4){0.f, 0.f, 0.f, 0.f};

        const f16x8* wb = (const f16x8*)Wp_pk + lane;
        f16x8 wcur[2];
#pragma unroll
        for (int j = 0; j < 2; ++j)
            wcur[j] = wb[(size_t)((nt0 + j) * KT) * 64];

        for (int kt = 0; kt < KT; ++kt) {
            const int ktn = (kt + 1 < KT) ? kt + 1 : KT - 1;
            f16x8 wnxt[2];
#pragma unroll
            for (int j = 0; j < 2; ++j)
                wnxt[j] = wb[(size_t)((nt0 + j) * KT + ktn) * 64];
            f16x8 xf[2];
#pragma unroll
            for (int tt = 0; tt < 2; ++tt)
                xf[tt] = *(const f16x8*)&S[(tt * 16 + l15) * QSTRIDE + kt * 32 + quad * 8];
#pragma unroll
            for (int j = 0; j < 2; ++j) {
                acc[0][j] = __builtin_amdgcn_mfma_f32_16x16x32_f16(wcur[j], xf[0], acc[0][j], 0, 0, 0);
                acc[1][j] = __builtin_amdgcn_mfma_f32_16x16x32_f16(wcur[j], xf[1], acc[1][j], 0, 0, 0);
            }
#pragma unroll
            for (int j = 0; j < 2; ++j) wcur[j] = wnxt[j];
        }
#pragma unroll
        for (int j = 0; j < 2; ++j) {
            f32x4 b = *(const f32x4*)&bp[(nt0 + j) * 16 + quad * 4];
#pragma unroll
            for (int tt = 0; tt < 2; ++tt) {
                f32x4 o = acc[tt][j] + b;
                *(f32x4*)&out[(token0 + tt * 16 + l15) * DIMX + (nt0 + j) * 16 + quad * 4] = o;
            }
        }
    }
}

extern "C" void kernel_launch(void* const* d_in, const int* in_sizes, int n_in,
                              void* d_out, int out_size, void* d_ws, size_t ws_size,
                              hipStream_t stream) {
    const float* v  = (const float*)d_in[0];
    const float* Wq = (const float*)d_in[1];
    const float* Wk = (const float*)d_in[2];
    const float* Wv = (const float*)d_in[3];
    const float* Wp = (const float*)d_in[4];
    const float* bp = (const float*)d_in[5];
    float* out = (float*)d_out;

    _Float16* pk = (_Float16*)d_ws;                // 32768 frags * 16 B = 512 KB
    const _Float16* Wqkv_pk = pk;                  // 24576 frags
    const _Float16* Wp_pk   = pk + (size_t)24576 * 8;

    pack_weights<<<256, 128, 0, stream>>>(Wq, Wk, Wv, Wp, pk);

    const int ntokens = in_sizes[0] / DIMX;        // 65536
    fused_attn_mfma<<<ntokens / TM, NTHREADS, 0, stream>>>(v, Wqkv_pk, Wp_pk, bp, out);
}